// Round 5
// baseline (28.444 us; speedup 1.0000x reference)
//
#include <hip/hip_runtime.h>
#include <math.h>

#define BB 2
#define SS 256
#define DD 256
#define EPSF 1e-6f

__device__ __forceinline__ float wave_scan_sum(float v, int lane) {
#pragma unroll
    for (int o = 1; o < 64; o <<= 1) {
        float u = __shfl_up(v, o);
        if (lane >= o) v += u;
    }
    return v;
}
__device__ __forceinline__ float wave_scan_prod(float v, int lane) {
#pragma unroll
    for (int o = 1; o < 64; o <<= 1) {
        float u = __shfl_up(v, o);
        if (lane >= o) v *= u;
    }
    return v;
}

// One kernel, no grid sync: 32 blocks x 1024 threads.
// Block = (batch b, 16 output rows i0..i0+15). Phase A recomputes the whole
// batch's LN-dots with full ILP (prefetch 16 rows/wave, 8-way interleaved
// shfl chains); phase B = one output row per wave.
__global__ __launch_bounds__(1024) void fused(
        const float* __restrict__ ctx,
        const float* __restrict__ ln_g, const float* __restrict__ ln_b,
        const float* __restrict__ fc_w, const float* __restrict__ prior,
        const float* __restrict__ fc_b,
        float* __restrict__ G, float* __restrict__ Mij) {
    __shared__ float dx1s[SS], dx2s[SS], P2s[SS];
    __shared__ float parts[4];

    const int t = threadIdx.x, wv = t >> 6, lane = t & 63;
    const int b  = blockIdx.x >> 4;           // 32 blocks: 16 per batch
    const int i0 = (blockIdx.x & 15) << 4;    // this block's output rows

    // scalars early (hide latency)
    const float pr = prior[0], fb = fc_b[0];

    // constant vectors (64 float4 each)
    const float4 g   = ((const float4*)ln_g)[lane];
    const float4 bbv = ((const float4*)ln_b)[lane];
    const float4 w1  = ((const float4*)fc_w)[lane];
    const float4 w2  = ((const float4*)fc_w)[64 + lane];
    const float gw1x = g.x * w1.x, gw1y = g.y * w1.y, gw1z = g.z * w1.z, gw1w = g.w * w1.w;
    const float gw2x = g.x * w2.x, gw2y = g.y * w2.y, gw2z = g.z * w2.z, gw2w = g.w * w2.w;

    // prefetch this wave's 16 ctx rows (independent loads, all in flight)
    const float4* ctx4 = (const float4*)ctx;
    float4 c[16];
#pragma unroll
    for (int j = 0; j < 16; ++j)
        c[j] = ctx4[(size_t)(b * SS + wv * 16 + j) * 64 + lane];

    // row-independent constants (4-way interleaved chain)
    float sg1 = gw1x + gw1y + gw1z + gw1w;
    float sg2 = gw2x + gw2y + gw2z + gw2w;
    float cb1 = bbv.x * w1.x + bbv.y * w1.y + bbv.z * w1.z + bbv.w * w1.w;
    float cb2 = bbv.x * w2.x + bbv.y * w2.y + bbv.z * w2.z + bbv.w * w2.w;
#pragma unroll
    for (int o = 32; o > 0; o >>= 1) {
        sg1 += __shfl_xor(sg1, o);
        sg2 += __shfl_xor(sg2, o);
        cb1 += __shfl_xor(cb1, o);
        cb2 += __shfl_xor(cb2, o);
    }

    // Phase A: 2 rows per chain, 8 interleaved accumulators
#pragma unroll
    for (int jp = 0; jp < 8; ++jp) {
        const float4 ca = c[2 * jp], cb = c[2 * jp + 1];
        float s0a = ca.x + ca.y + ca.z + ca.w;
        float s1a = ca.x * ca.x + ca.y * ca.y + ca.z * ca.z + ca.w * ca.w;
        float a1a = ca.x * gw1x + ca.y * gw1y + ca.z * gw1z + ca.w * gw1w;
        float a2a = ca.x * gw2x + ca.y * gw2y + ca.z * gw2z + ca.w * gw2w;
        float s0b = cb.x + cb.y + cb.z + cb.w;
        float s1b = cb.x * cb.x + cb.y * cb.y + cb.z * cb.z + cb.w * cb.w;
        float a1b = cb.x * gw1x + cb.y * gw1y + cb.z * gw1z + cb.w * gw1w;
        float a2b = cb.x * gw2x + cb.y * gw2y + cb.z * gw2z + cb.w * gw2w;
#pragma unroll
        for (int o = 32; o > 0; o >>= 1) {
            s0a += __shfl_xor(s0a, o);
            s1a += __shfl_xor(s1a, o);
            a1a += __shfl_xor(a1a, o);
            a2a += __shfl_xor(a2a, o);
            s0b += __shfl_xor(s0b, o);
            s1b += __shfl_xor(s1b, o);
            a1b += __shfl_xor(a1b, o);
            a2b += __shfl_xor(a2b, o);
        }
        if (lane == 0) {
            const int k0 = wv * 16 + 2 * jp;
            float mu  = s0a * (1.0f / DD);
            float var = (s1a - DD * mu * mu) * (1.0f / (DD - 1));
            float inv = 1.0f / (sqrtf(var) + EPSF);
            dx1s[k0] = (a1a - mu * sg1) * inv + cb1;
            dx2s[k0] = (a2a - mu * sg2) * inv + cb2;
            mu  = s0b * (1.0f / DD);
            var = (s1b - DD * mu * mu) * (1.0f / (DD - 1));
            inv = 1.0f / (sqrtf(var) + EPSF);
            dx1s[k0 + 1] = (a1b - mu * sg1) * inv + cb1;
            dx2s[k0 + 1] = (a2b - mu * sg2) * inv + cb2;
        }
    }
    __syncthreads();

    // block scan of dx2s -> P2s (waves 0-3)
    float incl = 0.0f;
    if (t < SS) {
        incl = wave_scan_sum(dx2s[t], lane);
        if (lane == 63) parts[wv] = incl;
    }
    __syncthreads();
    if (t < SS) {
        float pre = 0.0f;
        if (wv > 0) pre += parts[0];
        if (wv > 1) pre += parts[1];
        if (wv > 2) pre += parts[2];
        P2s[t] = incl + pre;
    }
    __syncthreads();

    // Phase B: wave wv -> output row i = i0 + wv
    const float mconst = pr + (1.0f - pr) / (1.0f + expf(-fb));
    const int i = i0 + wv;
    const float base = (i > 0) ? P2s[i - 1] : 0.0f;
    float carry = 1.0f;
    float* Grow = G   + (size_t)(b * SS + i) * SS;
    float* Mrow = Mij + (size_t)(b * SS + i) * SS;
#pragma unroll
    for (int cc = 0; cc < 4; ++cc) {
        const int k = cc * 64 + lane;
        float m;
        if (k >= i) {
            const float l = dx1s[k] + (P2s[k] - base) / (float)(k - i + 1) + fb;
            m = pr + (1.0f - pr) / (1.0f + expf(-l));
        } else {
            m = mconst;
        }
        Mrow[k] = m;
        const float v = (k >= i) ? m : 1.0f;
        const float p = wave_scan_prod(v, lane) * carry;
        carry = __shfl(p, 63);
        if (k == i) {
            Grow[k] = 1.0f;
        } else if (k > i) {
            Grow[k] = p;                              // row write, coalesced
            G[(size_t)(b * SS + k) * SS + i] = p;     // symmetric column write
        }
    }
}

extern "C" void kernel_launch(void* const* d_in, const int* in_sizes, int n_in,
                              void* d_out, int out_size, void* d_ws, size_t ws_size,
                              hipStream_t stream) {
    const float* ctx   = (const float*)d_in[0];
    // d_in[1] = eos_mask (unused by reference)
    const float* prior = (const float*)d_in[2];
    const float* ln_g  = (const float*)d_in[3];
    const float* ln_b  = (const float*)d_in[4];
    const float* fc_w  = (const float*)d_in[5];
    const float* fc_b  = (const float*)d_in[6];

    float* G   = (float*)d_out;                    // B*S*S
    float* Mij = (float*)d_out + BB * SS * SS;     // B*S*S

    fused<<<32, 1024, 0, stream>>>(ctx, ln_g, ln_b, fc_w, prior, fc_b, G, Mij);
}